// Round 5
// baseline (201.617 us; speedup 1.0000x reference)
//
#include <hip/hip_runtime.h>

#define BB 64
#define TT 512
#define HH 768
#define KK 11
#define START_ID 9
#define NEGV -10000.0f
#define TT4 (TT + 4)        // padded row stride for featsT
#define DH_REAL ((TT - 1) * 12)      // 6132 floats of real dh data
#define DH_STRIDE 6144               // per-batch dh_g row (floats, 16B aligned)

typedef float vf2 __attribute__((ext_vector_type(2)));

// ---------------------------------------------------------------------------
// DPP wave-64 sum reduction: row_shr 1/2/4/8 + row_bcast:15 + row_bcast:31.
// Result lands in lane 63. VALU-path only (no LDS).
// ---------------------------------------------------------------------------
template <int CTRL>
__device__ __forceinline__ float dpp_add(float x) {
    int yi = __builtin_amdgcn_update_dpp(0, __float_as_int(x), CTRL, 0xF, 0xF, false);
    return x + __int_as_float(yi);
}

__device__ __forceinline__ float wave_sum_to_lane63(float x) {
    x = dpp_add<0x111>(x);  // row_shr:1
    x = dpp_add<0x112>(x);  // row_shr:2
    x = dpp_add<0x114>(x);  // row_shr:4
    x = dpp_add<0x118>(x);  // row_shr:8  -> lane15 of each row16 = row sum
    x = dpp_add<0x142>(x);  // row_bcast:15
    x = dpp_add<0x143>(x);  // row_bcast:31 -> lane63 = full sum
    return x;
}

__device__ __forceinline__ float rlane(float v, int l) {
    return __int_as_float(__builtin_amdgcn_readlane(__float_as_int(v), l));
}

// ---------------------------------------------------------------------------
// FC v3 (unchanged from rounds 3/4): W in LDS (33 KB), embeds double-buffered
// in registers, k-loop W fragments software-pipelined one k ahead. Identical
// FP op sequence to v1 (bit-exact feats). No min-occupancy hint (round-2:
// __launch_bounds__(256,4) clamps VGPRs to 64 -> 145 MB scratch spill).
// ---------------------------------------------------------------------------
__global__ __launch_bounds__(256) void fc_kernel(const float* __restrict__ embeds,
                                                 const float* __restrict__ W,
                                                 const float* __restrict__ bias,
                                                 float* __restrict__ feats) {
    __shared__ __align__(16) float w_lds[KK * HH];  // 33 KB

    const int tid = threadIdx.x;
    const int lane = tid & 63;

    {
        const float4* src = reinterpret_cast<const float4*>(W);
        float4* dst = reinterpret_cast<float4*>(w_lds);
#pragma unroll
        for (int i = 0; i < 9; ++i) {
            int idx = tid + i * 256;
            if (idx < KK * HH / 4) dst[idx] = src[idx];
        }
    }

    float bk[KK];
#pragma unroll
    for (int k = 0; k < KK; ++k) bk[k] = bias[k];  // uniform -> SGPRs

    __syncthreads();

    const int wave_id = (blockIdx.x * blockDim.x + tid) >> 6;
    const int base = wave_id * 8;
    const int lo = lane * 4;

    const float* ea = embeds + (size_t)base * HH;
    const float* eb = ea + HH;
    float4 a0 = *reinterpret_cast<const float4*>(ea + 0   + lo);
    float4 a1 = *reinterpret_cast<const float4*>(ea + 256 + lo);
    float4 a2 = *reinterpret_cast<const float4*>(ea + 512 + lo);
    float4 b0 = *reinterpret_cast<const float4*>(eb + 0   + lo);
    float4 b1 = *reinterpret_cast<const float4*>(eb + 256 + lo);
    float4 b2 = *reinterpret_cast<const float4*>(eb + 512 + lo);

#pragma unroll 1
    for (int rr = 0; rr < 8; rr += 2) {
        const int nrr = (rr + 2) & 7;
        const float* na = embeds + (size_t)(base + nrr) * HH;
        const float* nb = na + HH;
        float4 na0 = *reinterpret_cast<const float4*>(na + 0   + lo);
        float4 na1 = *reinterpret_cast<const float4*>(na + 256 + lo);
        float4 na2 = *reinterpret_cast<const float4*>(na + 512 + lo);
        float4 nb0 = *reinterpret_cast<const float4*>(nb + 0   + lo);
        float4 nb1 = *reinterpret_cast<const float4*>(nb + 256 + lo);
        float4 nb2 = *reinterpret_cast<const float4*>(nb + 512 + lo);

        vf2 va[6] = {{a0.x, a0.y}, {a0.z, a0.w}, {a1.x, a1.y},
                     {a1.z, a1.w}, {a2.x, a2.y}, {a2.z, a2.w}};
        vf2 vb[6] = {{b0.x, b0.y}, {b0.z, b0.w}, {b1.x, b1.y},
                     {b1.z, b1.w}, {b2.x, b2.y}, {b2.z, b2.w}};

        float4 w0 = *reinterpret_cast<const float4*>(w_lds + 0 + lo);
        float4 w1 = *reinterpret_cast<const float4*>(w_lds + 256 + lo);
        float4 w2 = *reinterpret_cast<const float4*>(w_lds + 512 + lo);

        float rA[KK], rB[KK];
#pragma unroll
        for (int k = 0; k < KK; ++k) {
            const int nk = (k == KK - 1) ? 0 : k + 1;
            float4 nw0 = *reinterpret_cast<const float4*>(w_lds + nk * HH + 0 + lo);
            float4 nw1 = *reinterpret_cast<const float4*>(w_lds + nk * HH + 256 + lo);
            float4 nw2 = *reinterpret_cast<const float4*>(w_lds + nk * HH + 512 + lo);

            vf2 wv[6] = {{w0.x, w0.y}, {w0.z, w0.w},
                         {w1.x, w1.y}, {w1.z, w1.w},
                         {w2.x, w2.y}, {w2.z, w2.w}};
            vf2 sA = va[0] * wv[0];
            vf2 sB = vb[0] * wv[0];
#pragma unroll
            for (int r = 1; r < 6; ++r) { sA += va[r] * wv[r]; sB += vb[r] * wv[r]; }
            rA[k] = wave_sum_to_lane63(sA.x + sA.y);
            rB[k] = wave_sum_to_lane63(sB.x + sB.y);

            w0 = nw0; w1 = nw1; w2 = nw2;
        }

        if (lane == 63) {
            float* oA = feats + (size_t)(base + rr) * KK;
#pragma unroll
            for (int k = 0; k < KK; ++k) oA[k] = rA[k] + bk[k];
#pragma unroll
            for (int k = 0; k < KK; ++k) oA[KK + k] = rB[k] + bk[k];
        }

        a0 = na0; a1 = na1; a2 = na2;
        b0 = nb0; b1 = nb1; b2 = nb2;
    }
}

// ---------------------------------------------------------------------------
// Viterbi FORWARD (attribution split, part 1 of 2): stage-in transpose +
// phase-1 serial chain (verbatim round-4 logic, one characterized fix: dump
// lanes get DISTINCT scratch addresses -> kills the 23.5k same-address
// conflict cycles measured r0<->r4). dh history spilled to workspace for
// vit_back. score + last tag written to out.
// ---------------------------------------------------------------------------
__global__ __launch_bounds__(256) void vit_fwd(const float* __restrict__ feats,
                                               const float* __restrict__ trans,
                                               float* __restrict__ dh_g,
                                               float* __restrict__ out) {
    __shared__ __align__(16) float featsT[KK * TT4];          // transposed feats
    __shared__ __align__(16) float dh[DH_REAL + 64];          // stride 12; +scratch row
    __shared__ float tr_lds[KK * KK];

    const int tid = threadIdx.x;
    const int b = blockIdx.x;

    // ---- stage-in: transpose feats[b][t][k] -> featsT[k][t-1] ----
    {
        const float4* src = reinterpret_cast<const float4*>(feats + (size_t)b * TT * KK);
        for (int idx4 = tid; idx4 < TT * KK / 4; idx4 += 256) {
            float4 v = src[idx4];
            const int e = idx4 * 4;
#pragma unroll
            for (int u = 0; u < 4; ++u) {
                int t = (e + u) / KK;           // compile-time magic-div
                int k = (e + u) - t * KK;
                if (t > 0) featsT[k * TT4 + (t - 1)] = (&v.x)[u];
            }
        }
        if (tid < KK * KK) tr_lds[tid] = trans[tid];
    }
    __syncthreads();

    // ---- Phase 1: forward (wave 0 only) ----
    if (tid < 64) {
        const int i = tid;
        float tr[KK];
#pragma unroll
        for (int j = 0; j < KK; ++j) tr[j] = (i < KK) ? tr_lds[i * KK + j] : NEGV;

        float delta = (i == START_ID) ? 0.0f : NEGV;

        // unconditional dh store: real lanes walk stride 12; dump lanes pin to
        // DISTINCT scratch slots (<=2-way bank aliasing = free, m136), fixing
        // the 53-lane same-address serialization measured in round 4.
        int dhoff = (i < KK) ? i : (DH_REAL + (i - KK));
        const int dhstep = (i < KK) ? 12 : 0;

        auto vstep = [&](float fcur) {
            dh[dhoff] = delta;                  // pre-step delta (off-chain)
            dhoff += dhstep;
            float dj[KK];
#pragma unroll
            for (int j = 0; j < KK; ++j) dj[j] = rlane(delta, j);
            float s[KK];
#pragma unroll
            for (int j = 0; j < KK; ++j) s[j] = tr[j] + dj[j];
            float t0 = fmaxf(fmaxf(s[0], s[1]), s[2]);
            float t1 = fmaxf(fmaxf(s[3], s[4]), s[5]);
            float t2 = fmaxf(fmaxf(s[6], s[7]), s[8]);
            float t3 = fmaxf(s[9], s[10]);
            float best = fmaxf(fmaxf(fmaxf(t0, t1), t2), t3);
            delta = best + fcur;
        };

        auto chunk16 = [&](const float4& f0, const float4& f1,
                           const float4& f2, const float4& f3) {
            vstep(f0.x); vstep(f0.y); vstep(f0.z); vstep(f0.w);
            vstep(f1.x); vstep(f1.y); vstep(f1.z); vstep(f1.w);
            vstep(f2.x); vstep(f2.y); vstep(f2.z); vstep(f2.w);
            vstep(f3.x); vstep(f3.y); vstep(f3.z); vstep(f3.w);
        };

        const int ci = (i < KK) ? i : 0;
        const float* frow = featsT + ci * TT4;  // lane's contiguous time series

        float4 A0 = *reinterpret_cast<const float4*>(frow + 0);
        float4 A1 = *reinterpret_cast<const float4*>(frow + 4);
        float4 A2 = *reinterpret_cast<const float4*>(frow + 8);
        float4 A3 = *reinterpret_cast<const float4*>(frow + 12);

#pragma unroll 1
        for (int c = 0; c < 31; ++c) {
            const float* nf = frow + (c + 1) * 16;
            float4 B0 = *reinterpret_cast<const float4*>(nf + 0);
            float4 B1 = *reinterpret_cast<const float4*>(nf + 4);
            float4 B2 = *reinterpret_cast<const float4*>(nf + 8);
            float4 B3 = *reinterpret_cast<const float4*>(nf + 12);

            chunk16(A0, A1, A2, A3);            // pure VALU + dh writes

            A0 = B0; A1 = B1; A2 = B2; A3 = B3;
        }
        // tail: steps t=497..511 (15 steps; A3.w is the unused pad)
        vstep(A0.x); vstep(A0.y); vstep(A0.z); vstep(A0.w);
        vstep(A1.x); vstep(A1.y); vstep(A1.z); vstep(A1.w);
        vstep(A2.x); vstep(A2.y); vstep(A2.z); vstep(A2.w);
        vstep(A3.x); vstep(A3.y); vstep(A3.z);

        // score + last tag (strict-first argmax, exact)
        float dfin[KK];
#pragma unroll
        for (int j = 0; j < KK; ++j) dfin[j] = rlane(delta, j);
        float best = dfin[0];
        int last = 0;
#pragma unroll
        for (int j = 1; j < KK; ++j) {
            bool c = dfin[j] > best;
            best = c ? dfin[j] : best;
            last = c ? j : last;
        }
        if (tid == 0) {
            out[b] = best;
            out[BB + (size_t)b * TT + (TT - 1)] = (float)last;
        }
    }
    __syncthreads();

    // ---- spill dh history to workspace (coalesced, 24.5 KB) ----
    {
        const float4* src = reinterpret_cast<const float4*>(dh);
        float4* dst = reinterpret_cast<float4*>(dh_g + (size_t)b * DH_STRIDE);
        for (int idx = tid; idx < DH_REAL / 4; idx += 256) dst[idx] = src[idx];
    }
}

// ---------------------------------------------------------------------------
// Viterbi BACKWARD (attribution split, part 2 of 2): phases 2/3 verbatim from
// round 4, dh reloaded from workspace, last tag re-read from out.
// ---------------------------------------------------------------------------
__global__ __launch_bounds__(256) void vit_back(const float* __restrict__ dh_g,
                                                const float* __restrict__ trans,
                                                float* __restrict__ out) {
    __shared__ __align__(16) float dh[DH_REAL + 16];
    __shared__ int psi_lds[(TT - 1) * KK];
    __shared__ float tr_lds[KK * KK];
    __shared__ int comp[15 * KK];
    __shared__ int bt[16];
    __shared__ int sh_last;

    const int tid = threadIdx.x;
    const int b = blockIdx.x;

    {
        const float4* src = reinterpret_cast<const float4*>(dh_g + (size_t)b * DH_STRIDE);
        float4* dst = reinterpret_cast<float4*>(dh);
        for (int idx = tid; idx < DH_REAL / 4; idx += 256) dst[idx] = src[idx];
        if (tid < KK * KK) tr_lds[tid] = trans[tid];
        if (tid == 0) sh_last = (int)out[BB + (size_t)b * TT + (TT - 1)];
    }
    __syncthreads();

    // ---- Phase 2: psi recompute, parallel over (s, i) ----
    {
        const int i = tid & 15;
        const int sg = tid >> 4;
        if (i < KK) {
            float tri[KK];
#pragma unroll
            for (int j = 0; j < KK; ++j) tri[j] = tr_lds[i * KK + j];
            for (int s = sg; s < TT - 1; s += 16) {
                const float4* dr = reinterpret_cast<const float4*>(dh + s * 12);
                float4 a = dr[0], c4 = dr[1], d4 = dr[2];
                float sc[KK] = {tri[0] + a.x,  tri[1] + a.y,  tri[2] + a.z,  tri[3] + a.w,
                                tri[4] + c4.x, tri[5] + c4.y, tri[6] + c4.z, tri[7] + c4.w,
                                tri[8] + d4.x, tri[9] + d4.y, tri[10] + d4.z};
                float bv = sc[0];
                int bj = 0;
#pragma unroll
                for (int j = 1; j < KK; ++j) {
                    bool c = sc[j] > bv;        // strict: first max wins
                    bv = c ? sc[j] : bv;
                    bj = c ? j : bj;
                }
                psi_lds[s * KK + i] = bj;
            }
        }
    }
    __syncthreads();

    // ---- Phase 3a: chunk composition walks (0..14) + chunk 15 real walk ----
    {
        const int c = tid >> 4;
        const int i = tid & 15;
        if (c < 15 && i < KK) {
            int cur = i;
            for (int s = c * 32 + 31; s >= c * 32; --s) cur = psi_lds[s * KK + cur];
            comp[c * KK + i] = cur;            // path[32c] given path[32(c+1)] = i
        } else if (c == 15 && i == 0) {
            int cur = sh_last;
            float* po = out + BB + (size_t)b * TT;
            for (int s = TT - 2; s >= 480; --s) {
                cur = psi_lds[s * KK + cur];
                po[s] = (float)cur;
            }
            bt[15] = cur;                      // = path[480]
        }
    }
    __syncthreads();

    // ---- Phase 3b: boundary chain ----
    if (tid == 0) {
        for (int c = 14; c >= 1; --c) bt[c] = comp[c * KK + bt[c + 1]];
    }
    __syncthreads();

    // ---- Phase 3c: parallel re-walks, store path ----
    if (tid < 15) {
        const int c = tid;
        int cur = bt[c + 1];                   // path[32(c+1)]
        float* po = out + BB + (size_t)b * TT;
        for (int s = c * 32 + 31; s >= c * 32; --s) {
            cur = psi_lds[s * KK + cur];
            po[s] = (float)cur;
        }
    }
}

extern "C" void kernel_launch(void* const* d_in, const int* in_sizes, int n_in,
                              void* d_out, int out_size, void* d_ws, size_t ws_size,
                              hipStream_t stream) {
    const float* embeds = (const float*)d_in[0];  // [B,T,H]
    const float* W_fc   = (const float*)d_in[1];  // [K,H]
    const float* b_fc   = (const float*)d_in[2];  // [K]
    const float* trans  = (const float*)d_in[3];  // [K,K]
    float* out = (float*)d_out;                   // [B] score ++ [B,T] path (as float)
    float* feats = (float*)d_ws;                  // [B,T,K] scratch (1,441,792 B)
    float* dh_g  = (float*)((char*)d_ws + (size_t)BB * TT * KK * sizeof(float));
                                                  // [BB][DH_STRIDE] dh spill (1.57 MB)

    fc_kernel<<<1024, 256, 0, stream>>>(embeds, W_fc, b_fc, feats);
    vit_fwd<<<BB, 256, 0, stream>>>(feats, trans, dh_g, out);
    vit_back<<<BB, 256, 0, stream>>>(dh_g, trans, out);
}

// Round 6
// 195.754 us; speedup vs baseline: 1.0299x; 1.0299x over previous
//
#include <hip/hip_runtime.h>

#define BB 64
#define TT 512
#define HH 768
#define KK 11
#define START_ID 9
#define NEGV -10000.0f
#define TT4 (TT + 4)        // padded row stride for featsT

typedef float vf2 __attribute__((ext_vector_type(2)));

// ---------------------------------------------------------------------------
// DPP wave-64 sum reduction: row_shr 1/2/4/8 + row_bcast:15 + row_bcast:31.
// Result lands in lane 63. VALU-path only (no LDS).
// ---------------------------------------------------------------------------
template <int CTRL>
__device__ __forceinline__ float dpp_add(float x) {
    int yi = __builtin_amdgcn_update_dpp(0, __float_as_int(x), CTRL, 0xF, 0xF, false);
    return x + __int_as_float(yi);
}

__device__ __forceinline__ float wave_sum_to_lane63(float x) {
    x = dpp_add<0x111>(x);  // row_shr:1
    x = dpp_add<0x112>(x);  // row_shr:2
    x = dpp_add<0x114>(x);  // row_shr:4
    x = dpp_add<0x118>(x);  // row_shr:8  -> lane15 of each row16 = row sum
    x = dpp_add<0x142>(x);  // row_bcast:15
    x = dpp_add<0x143>(x);  // row_bcast:31 -> lane63 = full sum
    return x;
}

__device__ __forceinline__ float rlane(float v, int l) {
    return __int_as_float(__builtin_amdgcn_readlane(__float_as_int(v), l));
}

// ---------------------------------------------------------------------------
// FC v3 (unchanged since round 3): W in LDS (33 KB), embeds double-buffered
// in registers, k-loop W fragments software-pipelined one k ahead. Identical
// FP op sequence to v1 (bit-exact feats). No min-occupancy hint (round-2:
// __launch_bounds__(256,4) clamps VGPRs to 64 -> 145 MB scratch spill).
// ---------------------------------------------------------------------------
__global__ __launch_bounds__(256) void fc_kernel(const float* __restrict__ embeds,
                                                 const float* __restrict__ W,
                                                 const float* __restrict__ bias,
                                                 float* __restrict__ feats) {
    __shared__ __align__(16) float w_lds[KK * HH];  // 33 KB

    const int tid = threadIdx.x;
    const int lane = tid & 63;

    {
        const float4* src = reinterpret_cast<const float4*>(W);
        float4* dst = reinterpret_cast<float4*>(w_lds);
#pragma unroll
        for (int i = 0; i < 9; ++i) {
            int idx = tid + i * 256;
            if (idx < KK * HH / 4) dst[idx] = src[idx];
        }
    }

    float bk[KK];
#pragma unroll
    for (int k = 0; k < KK; ++k) bk[k] = bias[k];  // uniform -> SGPRs

    __syncthreads();

    const int wave_id = (blockIdx.x * blockDim.x + tid) >> 6;
    const int base = wave_id * 8;
    const int lo = lane * 4;

    const float* ea = embeds + (size_t)base * HH;
    const float* eb = ea + HH;
    float4 a0 = *reinterpret_cast<const float4*>(ea + 0   + lo);
    float4 a1 = *reinterpret_cast<const float4*>(ea + 256 + lo);
    float4 a2 = *reinterpret_cast<const float4*>(ea + 512 + lo);
    float4 b0 = *reinterpret_cast<const float4*>(eb + 0   + lo);
    float4 b1 = *reinterpret_cast<const float4*>(eb + 256 + lo);
    float4 b2 = *reinterpret_cast<const float4*>(eb + 512 + lo);

#pragma unroll 1
    for (int rr = 0; rr < 8; rr += 2) {
        const int nrr = (rr + 2) & 7;
        const float* na = embeds + (size_t)(base + nrr) * HH;
        const float* nb = na + HH;
        float4 na0 = *reinterpret_cast<const float4*>(na + 0   + lo);
        float4 na1 = *reinterpret_cast<const float4*>(na + 256 + lo);
        float4 na2 = *reinterpret_cast<const float4*>(na + 512 + lo);
        float4 nb0 = *reinterpret_cast<const float4*>(nb + 0   + lo);
        float4 nb1 = *reinterpret_cast<const float4*>(nb + 256 + lo);
        float4 nb2 = *reinterpret_cast<const float4*>(nb + 512 + lo);

        vf2 va[6] = {{a0.x, a0.y}, {a0.z, a0.w}, {a1.x, a1.y},
                     {a1.z, a1.w}, {a2.x, a2.y}, {a2.z, a2.w}};
        vf2 vb[6] = {{b0.x, b0.y}, {b0.z, b0.w}, {b1.x, b1.y},
                     {b1.z, b1.w}, {b2.x, b2.y}, {b2.z, b2.w}};

        float4 w0 = *reinterpret_cast<const float4*>(w_lds + 0 + lo);
        float4 w1 = *reinterpret_cast<const float4*>(w_lds + 256 + lo);
        float4 w2 = *reinterpret_cast<const float4*>(w_lds + 512 + lo);

        float rA[KK], rB[KK];
#pragma unroll
        for (int k = 0; k < KK; ++k) {
            const int nk = (k == KK - 1) ? 0 : k + 1;
            float4 nw0 = *reinterpret_cast<const float4*>(w_lds + nk * HH + 0 + lo);
            float4 nw1 = *reinterpret_cast<const float4*>(w_lds + nk * HH + 256 + lo);
            float4 nw2 = *reinterpret_cast<const float4*>(w_lds + nk * HH + 512 + lo);

            vf2 wv[6] = {{w0.x, w0.y}, {w0.z, w0.w},
                         {w1.x, w1.y}, {w1.z, w1.w},
                         {w2.x, w2.y}, {w2.z, w2.w}};
            vf2 sA = va[0] * wv[0];
            vf2 sB = vb[0] * wv[0];
#pragma unroll
            for (int r = 1; r < 6; ++r) { sA += va[r] * wv[r]; sB += vb[r] * wv[r]; }
            rA[k] = wave_sum_to_lane63(sA.x + sA.y);
            rB[k] = wave_sum_to_lane63(sB.x + sB.y);

            w0 = nw0; w1 = nw1; w2 = nw2;
        }

        if (lane == 63) {
            float* oA = feats + (size_t)(base + rr) * KK;
#pragma unroll
            for (int k = 0; k < KK; ++k) oA[k] = rA[k] + bk[k];
#pragma unroll
            for (int k = 0; k < KK; ++k) oA[KK + k] = rB[k] + bk[k];
        }

        a0 = na0; a1 = na1; a2 = na2;
        b0 = nb0; b1 = nb1; b2 = nb2;
    }
}

// ---------------------------------------------------------------------------
// Viterbi v6 (merged again): the phase-1 serial chain touches NO LDS at all.
//   - feats staged transposed (featsT[k][t-1]); chunk-ahead ds_read_b128
//     ping-pong for fcur (round-4 structure, reads retired a chunk early).
//   - NEW: per-step delta history goes to named registers h0..h15 (v_mov,
//     off-chain). The 11 real lanes flush all 16 with constant-offset
//     ds_writes once per chunk; h-reg WAR reuse is a full chunk (~900 cyc)
//     after the write -> no lgkmcnt wait ever lands on the chain. Dump lanes
//     never write (kills round-4's same-address conflict regression).
// Phases 2/3 verbatim. FP op sequence identical -> bit-exact.
// ---------------------------------------------------------------------------
__global__ __launch_bounds__(256) void viterbi_kernel(const float* __restrict__ feats,
                                                      const float* __restrict__ trans,
                                                      float* __restrict__ out) {
    __shared__ __align__(16) float featsT[KK * TT4];          // transposed feats
    __shared__ __align__(16) float dh[(TT - 1) * 12 + 16];    // stride 12
    __shared__ int psi_lds[(TT - 1) * KK];
    __shared__ float tr_lds[KK * KK];
    __shared__ int comp[15 * KK];
    __shared__ int bt[16];
    __shared__ int sh_last;

    const int tid = threadIdx.x;
    const int b = blockIdx.x;

    // ---- stage-in: transpose feats[b][t][k] -> featsT[k][t-1] ----
    {
        const float4* src = reinterpret_cast<const float4*>(feats + (size_t)b * TT * KK);
        for (int idx4 = tid; idx4 < TT * KK / 4; idx4 += 256) {
            float4 v = src[idx4];
            const int e = idx4 * 4;
#pragma unroll
            for (int u = 0; u < 4; ++u) {
                int t = (e + u) / KK;           // compile-time magic-div
                int k = (e + u) - t * KK;
                if (t > 0) featsT[k * TT4 + (t - 1)] = (&v.x)[u];
            }
        }
        if (tid < KK * KK) tr_lds[tid] = trans[tid];
    }
    __syncthreads();

    // ---- Phase 1: forward (wave 0 only), zero-LDS serial chain ----
    if (tid < 64) {
        const int i = tid;
        float tr[KK];
#pragma unroll
        for (int j = 0; j < KK; ++j) tr[j] = (i < KK) ? tr_lds[i * KK + j] : NEGV;

        float delta = (i == START_ID) ? 0.0f : NEGV;

        // pure-register step: history slot written by v_mov, no memory op
        auto vstep = [&](float fcur, float& hs) {
            hs = delta;                         // pre-step delta -> register
            float dj[KK];
#pragma unroll
            for (int j = 0; j < KK; ++j) dj[j] = rlane(delta, j);
            float s[KK];
#pragma unroll
            for (int j = 0; j < KK; ++j) s[j] = tr[j] + dj[j];
            float t0 = fmaxf(fmaxf(s[0], s[1]), s[2]);
            float t1 = fmaxf(fmaxf(s[3], s[4]), s[5]);
            float t2 = fmaxf(fmaxf(s[6], s[7]), s[8]);
            float t3 = fmaxf(s[9], s[10]);
            float best = fmaxf(fmaxf(fmaxf(t0, t1), t2), t3);
            delta = best + fcur;
        };

        const int ci = (i < KK) ? i : 0;
        const float* frow = featsT + ci * TT4;  // lane's contiguous time series
        float* dwbase = dh + i;                 // only dereferenced when i < KK

        float h0, h1, h2, h3, h4, h5, h6, h7;
        float h8, h9, h10, h11, h12, h13, h14, h15;

        float4 A0 = *reinterpret_cast<const float4*>(frow + 0);
        float4 A1 = *reinterpret_cast<const float4*>(frow + 4);
        float4 A2 = *reinterpret_cast<const float4*>(frow + 8);
        float4 A3 = *reinterpret_cast<const float4*>(frow + 12);

#pragma unroll 1
        for (int c = 0; c < 31; ++c) {
            const float* nf = frow + (c + 1) * 16;
            float4 B0 = *reinterpret_cast<const float4*>(nf + 0);
            float4 B1 = *reinterpret_cast<const float4*>(nf + 4);
            float4 B2 = *reinterpret_cast<const float4*>(nf + 8);
            float4 B3 = *reinterpret_cast<const float4*>(nf + 12);

            vstep(A0.x, h0);  vstep(A0.y, h1);  vstep(A0.z, h2);  vstep(A0.w, h3);
            vstep(A1.x, h4);  vstep(A1.y, h5);  vstep(A1.z, h6);  vstep(A1.w, h7);
            vstep(A2.x, h8);  vstep(A2.y, h9);  vstep(A2.z, h10); vstep(A2.w, h11);
            vstep(A3.x, h12); vstep(A3.y, h13); vstep(A3.z, h14); vstep(A3.w, h15);

            // batched history flush: 16 ds_writes, constant offsets, 11 lanes,
            // 11 distinct banks. Fire-and-forget; h-reg reuse is next chunk.
            if (i < KK) {
                float* dw = dwbase + c * 192;   // (c*16 + m)*12 + i
                dw[0]   = h0;  dw[12]  = h1;  dw[24]  = h2;  dw[36]  = h3;
                dw[48]  = h4;  dw[60]  = h5;  dw[72]  = h6;  dw[84]  = h7;
                dw[96]  = h8;  dw[108] = h9;  dw[120] = h10; dw[132] = h11;
                dw[144] = h12; dw[156] = h13; dw[168] = h14; dw[180] = h15;
            }

            A0 = B0; A1 = B1; A2 = B2; A3 = B3;
        }
        // tail: steps t=497..511 (15 steps; A3.w is the unused pad)
        vstep(A0.x, h0);  vstep(A0.y, h1);  vstep(A0.z, h2);  vstep(A0.w, h3);
        vstep(A1.x, h4);  vstep(A1.y, h5);  vstep(A1.z, h6);  vstep(A1.w, h7);
        vstep(A2.x, h8);  vstep(A2.y, h9);  vstep(A2.z, h10); vstep(A2.w, h11);
        vstep(A3.x, h12); vstep(A3.y, h13); vstep(A3.z, h14);
        if (i < KK) {
            float* dw = dwbase + 31 * 192;      // s = 496..510
            dw[0]   = h0;  dw[12]  = h1;  dw[24]  = h2;  dw[36]  = h3;
            dw[48]  = h4;  dw[60]  = h5;  dw[72]  = h6;  dw[84]  = h7;
            dw[96]  = h8;  dw[108] = h9;  dw[120] = h10; dw[132] = h11;
            dw[144] = h12; dw[156] = h13; dw[168] = h14;
        }

        // score + last tag (strict-first argmax, exact)
        float dfin[KK];
#pragma unroll
        for (int j = 0; j < KK; ++j) dfin[j] = rlane(delta, j);
        float best = dfin[0];
        int last = 0;
#pragma unroll
        for (int j = 1; j < KK; ++j) {
            bool c = dfin[j] > best;
            best = c ? dfin[j] : best;
            last = c ? j : last;
        }
        if (tid == 0) {
            out[b] = best;
            out[BB + (size_t)b * TT + (TT - 1)] = (float)last;
            sh_last = last;
        }
    }
    __syncthreads();

    // ---- Phase 2: psi recompute, parallel over (s, i) ----
    {
        const int i = tid & 15;
        const int sg = tid >> 4;
        if (i < KK) {
            float tri[KK];
#pragma unroll
            for (int j = 0; j < KK; ++j) tri[j] = tr_lds[i * KK + j];
            for (int s = sg; s < TT - 1; s += 16) {
                const float4* dr = reinterpret_cast<const float4*>(dh + s * 12);
                float4 a = dr[0], c4 = dr[1], d4 = dr[2];
                float sc[KK] = {tri[0] + a.x,  tri[1] + a.y,  tri[2] + a.z,  tri[3] + a.w,
                                tri[4] + c4.x, tri[5] + c4.y, tri[6] + c4.z, tri[7] + c4.w,
                                tri[8] + d4.x, tri[9] + d4.y, tri[10] + d4.z};
                float bv = sc[0];
                int bj = 0;
#pragma unroll
                for (int j = 1; j < KK; ++j) {
                    bool c = sc[j] > bv;        // strict: first max wins
                    bv = c ? sc[j] : bv;
                    bj = c ? j : bj;
                }
                psi_lds[s * KK + i] = bj;
            }
        }
    }
    __syncthreads();

    // ---- Phase 3a: chunk composition walks (0..14) + chunk 15 real walk ----
    {
        const int c = tid >> 4;
        const int i = tid & 15;
        if (c < 15 && i < KK) {
            int cur = i;
            for (int s = c * 32 + 31; s >= c * 32; --s) cur = psi_lds[s * KK + cur];
            comp[c * KK + i] = cur;            // path[32c] given path[32(c+1)] = i
        } else if (c == 15 && i == 0) {
            int cur = sh_last;
            float* po = out + BB + (size_t)b * TT;
            for (int s = TT - 2; s >= 480; --s) {
                cur = psi_lds[s * KK + cur];
                po[s] = (float)cur;
            }
            bt[15] = cur;                      // = path[480]
        }
    }
    __syncthreads();

    // ---- Phase 3b: boundary chain ----
    if (tid == 0) {
        for (int c = 14; c >= 1; --c) bt[c] = comp[c * KK + bt[c + 1]];
    }
    __syncthreads();

    // ---- Phase 3c: parallel re-walks, store path ----
    if (tid < 15) {
        const int c = tid;
        int cur = bt[c + 1];                   // path[32(c+1)]
        float* po = out + BB + (size_t)b * TT;
        for (int s = c * 32 + 31; s >= c * 32; --s) {
            cur = psi_lds[s * KK + cur];
            po[s] = (float)cur;
        }
    }
}

extern "C" void kernel_launch(void* const* d_in, const int* in_sizes, int n_in,
                              void* d_out, int out_size, void* d_ws, size_t ws_size,
                              hipStream_t stream) {
    const float* embeds = (const float*)d_in[0];  // [B,T,H]
    const float* W_fc   = (const float*)d_in[1];  // [K,H]
    const float* b_fc   = (const float*)d_in[2];  // [K]
    const float* trans  = (const float*)d_in[3];  // [K,K]
    float* out = (float*)d_out;                   // [B] score ++ [B,T] path (as float)
    float* feats = (float*)d_ws;                  // [B,T,K] scratch

    fc_kernel<<<1024, 256, 0, stream>>>(embeds, W_fc, b_fc, feats);
    viterbi_kernel<<<BB, 256, 0, stream>>>(feats, trans, out);
}